// Round 8
// baseline (271.440 us; speedup 1.0000x reference)
//
#include <hip/hip_runtime.h>
#include <hip/hip_bf16.h>
#include <math.h>

// Problem: B=1, N=1024, D=1024, H=16, C=64, TOPK=2, HD=64, G=16
// Inputs (float32): x, Wq, Wk, Wv [1024x1024], Wg[32,1024], Wo[1024,1024]
// Output (float32): [1024,1024]
//
// Numerics: bf16x2 split (hi/lo) MFMA GEMMs: Ah*Bh + Ah*Bl + Al*Bh, f32 acc.
// Operands PRE-SPLIT once into global bf16 buffers; GEMM K-loop is pure
// m97-style: global_load_lds(16B) staging + ds_read_b128 + 12 MFMA/iter.
// Attention exact f32, fused (inter 2 blocks + causal intra + gated blend).

typedef __attribute__((ext_vector_type(8))) short short8;   // 8 bf16 = 4 VGPRs
typedef __attribute__((ext_vector_type(4))) float f32x4;

#define NTOK 1024
#define DMODEL 1024
#define NHEAD 16
#define HDIM 64
#define CHUNK 64
#define NBLK 16

// async global->LDS, 16 bytes per lane; LDS dest is wave-uniform base + lane*16
__device__ __forceinline__ void load_lds16(const void* gptr, void* lptr)
{
    __builtin_amdgcn_global_load_lds(
        (const __attribute__((address_space(1))) unsigned int*)gptr,
        (__attribute__((address_space(3))) unsigned int*)lptr, 16, 0, 0);
}

// ---------------------------------------------------------------------------
// split cast: hi = bf16(v), lo = bf16(v - hi);  4 elems/thread
// ---------------------------------------------------------------------------
__global__ __launch_bounds__(256) void cast_split_f32_bf16(
    const float* __restrict__ in, __hip_bfloat16* __restrict__ hi,
    __hip_bfloat16* __restrict__ lo, int n)
{
    int i = (blockIdx.x * 256 + threadIdx.x) * 4;
    if (i < n) {
        float4 v = *(const float4*)(in + i);
        float vv[4] = {v.x, v.y, v.z, v.w};
        __hip_bfloat16 h[4], l[4];
        #pragma unroll
        for (int j = 0; j < 4; j++) {
            h[j] = __float2bfloat16(vv[j]);
            l[j] = __float2bfloat16(vv[j] - __bfloat162float(h[j]));
        }
        *(uint2*)(hi + i) = *(uint2*)h;
        *(uint2*)(lo + i) = *(uint2*)l;
    }
}

// ---------------------------------------------------------------------------
// Pre-split QKV GEMM. A = x (hi/lo bf16), B = W3 (Wq|Wk|Wv stacked, hi/lo).
// blockIdx.x in [0,48): widx = x>>4 selects W and output.
// 64x64 tile; per K-iter: 4x global_load_lds(4KB tiles), 8 ds_read_b128,
// 12 mfma_16x16x32_bf16 (lo*lo dropped).
// ---------------------------------------------------------------------------
__global__ __launch_bounds__(256) void gemm_qkv_ps(
    const __hip_bfloat16* __restrict__ xh, const __hip_bfloat16* __restrict__ xl,
    const __hip_bfloat16* __restrict__ W3h, const __hip_bfloat16* __restrict__ W3l,
    float* __restrict__ Q, float* __restrict__ K, float* __restrict__ V)
{
    __shared__ alignas(16) __hip_bfloat16 Ash[64][32];
    __shared__ alignas(16) __hip_bfloat16 Asl[64][32];
    __shared__ alignas(16) __hip_bfloat16 Bsh[64][32];
    __shared__ alignas(16) __hip_bfloat16 Bsl[64][32];

    const int widx = blockIdx.x >> 4;
    const __hip_bfloat16* __restrict__ Bh = W3h + (size_t)widx * NTOK * DMODEL;
    const __hip_bfloat16* __restrict__ Bl = W3l + (size_t)widx * NTOK * DMODEL;
    float* __restrict__ C = (widx == 0) ? Q : (widx == 1) ? K : V;
    const int n0 = (blockIdx.x & 15) * 64;
    const int m0 = blockIdx.y * 64;

    const int tid  = threadIdx.x;
    const int wave = tid >> 6;
    const int lane = tid & 63;
    const int lr = tid >> 2;          // staging row 0..63
    const int lc = (tid & 3) * 8;     // staging col (bf16)
    const int wm = (wave >> 1) * 32;
    const int wn = (wave & 1) * 32;
    const int fr = lane & 15;
    const int quad = lane >> 4;

    // per-thread LDS dest: base + tid*16B  (== &tile[lr][lc], row-major [64][32])
    __hip_bfloat16* ldsA_h = &Ash[0][0] + tid * 8;
    __hip_bfloat16* ldsA_l = &Asl[0][0] + tid * 8;
    __hip_bfloat16* ldsB_h = &Bsh[0][0] + tid * 8;
    __hip_bfloat16* ldsB_l = &Bsl[0][0] + tid * 8;

    f32x4 acc[2][2] = {};

    for (int k0 = 0; k0 < DMODEL; k0 += 32) {
        const size_t aoff = (size_t)(m0 + lr) * DMODEL + k0 + lc;
        const size_t boff = (size_t)(n0 + lr) * DMODEL + k0 + lc;
        load_lds16(xh + aoff, ldsA_h);
        load_lds16(xl + aoff, ldsA_l);
        load_lds16(Bh + boff, ldsB_h);
        load_lds16(Bl + boff, ldsB_l);
        __syncthreads();

        short8 a0h = *(const short8*)(&Ash[wm + fr][quad * 8]);
        short8 a1h = *(const short8*)(&Ash[wm + 16 + fr][quad * 8]);
        short8 a0l = *(const short8*)(&Asl[wm + fr][quad * 8]);
        short8 a1l = *(const short8*)(&Asl[wm + 16 + fr][quad * 8]);
        short8 b0h = *(const short8*)(&Bsh[wn + fr][quad * 8]);
        short8 b1h = *(const short8*)(&Bsh[wn + 16 + fr][quad * 8]);
        short8 b0l = *(const short8*)(&Bsl[wn + fr][quad * 8]);
        short8 b1l = *(const short8*)(&Bsl[wn + 16 + fr][quad * 8]);

        acc[0][0] = __builtin_amdgcn_mfma_f32_16x16x32_bf16(a0l, b0h, acc[0][0], 0, 0, 0);
        acc[0][1] = __builtin_amdgcn_mfma_f32_16x16x32_bf16(a0l, b1h, acc[0][1], 0, 0, 0);
        acc[1][0] = __builtin_amdgcn_mfma_f32_16x16x32_bf16(a1l, b0h, acc[1][0], 0, 0, 0);
        acc[1][1] = __builtin_amdgcn_mfma_f32_16x16x32_bf16(a1l, b1h, acc[1][1], 0, 0, 0);
        acc[0][0] = __builtin_amdgcn_mfma_f32_16x16x32_bf16(a0h, b0l, acc[0][0], 0, 0, 0);
        acc[0][1] = __builtin_amdgcn_mfma_f32_16x16x32_bf16(a0h, b1l, acc[0][1], 0, 0, 0);
        acc[1][0] = __builtin_amdgcn_mfma_f32_16x16x32_bf16(a1h, b0l, acc[1][0], 0, 0, 0);
        acc[1][1] = __builtin_amdgcn_mfma_f32_16x16x32_bf16(a1h, b1l, acc[1][1], 0, 0, 0);
        acc[0][0] = __builtin_amdgcn_mfma_f32_16x16x32_bf16(a0h, b0h, acc[0][0], 0, 0, 0);
        acc[0][1] = __builtin_amdgcn_mfma_f32_16x16x32_bf16(a0h, b1h, acc[0][1], 0, 0, 0);
        acc[1][0] = __builtin_amdgcn_mfma_f32_16x16x32_bf16(a1h, b0h, acc[1][0], 0, 0, 0);
        acc[1][1] = __builtin_amdgcn_mfma_f32_16x16x32_bf16(a1h, b1h, acc[1][1], 0, 0, 0);
        __syncthreads();
    }

    // C/D layout: col = lane&15, row = (lane>>4)*4 + reg
    #pragma unroll
    for (int tm = 0; tm < 2; tm++)
    #pragma unroll
    for (int tn = 0; tn < 2; tn++)
    #pragma unroll
    for (int r = 0; r < 4; r++) {
        int row = m0 + wm + tm * 16 + quad * 4 + r;
        int col = n0 + wn + tn * 16 + fr;
        C[(size_t)row * DMODEL + col] = acc[tm][tn][r];
    }
}

// ---------------------------------------------------------------------------
// Pre-split Wo GEMM, split-K=2, atomicAdd into zeroed C.
// ---------------------------------------------------------------------------
__global__ __launch_bounds__(256) void gemm_wo_ps(
    const __hip_bfloat16* __restrict__ Ah, const __hip_bfloat16* __restrict__ Al,
    const __hip_bfloat16* __restrict__ Bh, const __hip_bfloat16* __restrict__ Bl,
    float* __restrict__ C)
{
    __shared__ alignas(16) __hip_bfloat16 Ash[64][32];
    __shared__ alignas(16) __hip_bfloat16 Asl[64][32];
    __shared__ alignas(16) __hip_bfloat16 Bsh[64][32];
    __shared__ alignas(16) __hip_bfloat16 Bsl[64][32];

    const int n0 = blockIdx.x * 64;
    const int m0 = blockIdx.y * 64;
    const int kbeg = blockIdx.z * (DMODEL / 2);
    const int kend = kbeg + (DMODEL / 2);

    const int tid  = threadIdx.x;
    const int wave = tid >> 6;
    const int lane = tid & 63;
    const int lr = tid >> 2;
    const int lc = (tid & 3) * 8;
    const int wm = (wave >> 1) * 32;
    const int wn = (wave & 1) * 32;
    const int fr = lane & 15;
    const int quad = lane >> 4;

    __hip_bfloat16* ldsA_h = &Ash[0][0] + tid * 8;
    __hip_bfloat16* ldsA_l = &Asl[0][0] + tid * 8;
    __hip_bfloat16* ldsB_h = &Bsh[0][0] + tid * 8;
    __hip_bfloat16* ldsB_l = &Bsl[0][0] + tid * 8;

    f32x4 acc[2][2] = {};

    for (int k0 = kbeg; k0 < kend; k0 += 32) {
        const size_t aoff = (size_t)(m0 + lr) * DMODEL + k0 + lc;
        const size_t boff = (size_t)(n0 + lr) * DMODEL + k0 + lc;
        load_lds16(Ah + aoff, ldsA_h);
        load_lds16(Al + aoff, ldsA_l);
        load_lds16(Bh + boff, ldsB_h);
        load_lds16(Bl + boff, ldsB_l);
        __syncthreads();

        short8 a0h = *(const short8*)(&Ash[wm + fr][quad * 8]);
        short8 a1h = *(const short8*)(&Ash[wm + 16 + fr][quad * 8]);
        short8 a0l = *(const short8*)(&Asl[wm + fr][quad * 8]);
        short8 a1l = *(const short8*)(&Asl[wm + 16 + fr][quad * 8]);
        short8 b0h = *(const short8*)(&Bsh[wn + fr][quad * 8]);
        short8 b1h = *(const short8*)(&Bsh[wn + 16 + fr][quad * 8]);
        short8 b0l = *(const short8*)(&Bsl[wn + fr][quad * 8]);
        short8 b1l = *(const short8*)(&Bsl[wn + 16 + fr][quad * 8]);

        acc[0][0] = __builtin_amdgcn_mfma_f32_16x16x32_bf16(a0l, b0h, acc[0][0], 0, 0, 0);
        acc[0][1] = __builtin_amdgcn_mfma_f32_16x16x32_bf16(a0l, b1h, acc[0][1], 0, 0, 0);
        acc[1][0] = __builtin_amdgcn_mfma_f32_16x16x32_bf16(a1l, b0h, acc[1][0], 0, 0, 0);
        acc[1][1] = __builtin_amdgcn_mfma_f32_16x16x32_bf16(a1l, b1h, acc[1][1], 0, 0, 0);
        acc[0][0] = __builtin_amdgcn_mfma_f32_16x16x32_bf16(a0h, b0l, acc[0][0], 0, 0, 0);
        acc[0][1] = __builtin_amdgcn_mfma_f32_16x16x32_bf16(a0h, b1l, acc[0][1], 0, 0, 0);
        acc[1][0] = __builtin_amdgcn_mfma_f32_16x16x32_bf16(a1h, b0l, acc[1][0], 0, 0, 0);
        acc[1][1] = __builtin_amdgcn_mfma_f32_16x16x32_bf16(a1h, b1l, acc[1][1], 0, 0, 0);
        acc[0][0] = __builtin_amdgcn_mfma_f32_16x16x32_bf16(a0h, b0h, acc[0][0], 0, 0, 0);
        acc[0][1] = __builtin_amdgcn_mfma_f32_16x16x32_bf16(a0h, b1h, acc[0][1], 0, 0, 0);
        acc[1][0] = __builtin_amdgcn_mfma_f32_16x16x32_bf16(a1h, b0h, acc[1][0], 0, 0, 0);
        acc[1][1] = __builtin_amdgcn_mfma_f32_16x16x32_bf16(a1h, b1h, acc[1][1], 0, 0, 0);
        __syncthreads();
    }

    #pragma unroll
    for (int tm = 0; tm < 2; tm++)
    #pragma unroll
    for (int tn = 0; tn < 2; tn++)
    #pragma unroll
    for (int r = 0; r < 4; r++) {
        int row = m0 + wm + tm * 16 + quad * 4 + r;
        int col = n0 + wn + tn * 16 + fr;
        atomicAdd(&C[(size_t)row * DMODEL + col], acc[tm][tn][r]);
    }
}

// ---------------------------------------------------------------------------
// Gate: softmax((x @ Wg^T).reshape(n, 16, 2), axis=-1) -> float2 per (n,h)
// ---------------------------------------------------------------------------
__global__ __launch_bounds__(256) void gate_kernel(
    const float* __restrict__ x,
    const float* __restrict__ Wg,
    float2* __restrict__ gate)
{
    __shared__ float gs[32];
    const int n = blockIdx.x;
    const int wave = threadIdx.x >> 6, lane = threadIdx.x & 63;
    #pragma unroll
    for (int jj = 0; jj < 8; jj++) {
        int j = wave * 8 + jj;
        float s = 0.f;
        #pragma unroll
        for (int t = 0; t < 16; t++) {
            int d = lane + (t << 6);
            s += x[n * DMODEL + d] * Wg[j * DMODEL + d];
        }
        #pragma unroll
        for (int off = 32; off; off >>= 1) s += __shfl_xor(s, off);
        if (lane == 0) gs[j] = s;
    }
    __syncthreads();
    if (threadIdx.x < NHEAD) {
        int h = threadIdx.x;
        float a = gs[2 * h], b = gs[2 * h + 1];
        float m = fmaxf(a, b);
        float ea = expf(a - m), eb = expf(b - m);
        float inv = 1.f / (ea + eb);
        gate[n * NHEAD + h] = make_float2(ea * inv, eb * inv);
    }
}

// ---------------------------------------------------------------------------
// k_compress[g][f] = mean over c of K[g*64+c][f]
// ---------------------------------------------------------------------------
__global__ __launch_bounds__(256) void kcompress_kernel(
    const float* __restrict__ K, float* __restrict__ kc)
{
    const int g = blockIdx.x;
    for (int f = threadIdx.x; f < DMODEL; f += 256) {
        float s = 0.f;
        #pragma unroll 8
        for (int c = 0; c < CHUNK; c++) s += K[(size_t)(g * CHUNK + c) * DMODEL + f];
        kc[g * DMODEL + f] = s * (1.0f / CHUNK);
    }
}

// ---------------------------------------------------------------------------
// Per-head transpose: Kt[(h*64+d)*1024 + n] = K[n*1024 + h*64 + d]
// ---------------------------------------------------------------------------
__global__ __launch_bounds__(256) void transpose_k_kernel(
    const float* __restrict__ K, float* __restrict__ Kt)
{
    __shared__ float T[64][65];
    const int h = blockIdx.x & 15;
    const int n0 = (blockIdx.x >> 4) * 64;
    for (int i = threadIdx.x; i < 64 * 64; i += 256) {
        int r = i >> 6, d = i & 63;
        T[r][d] = K[(size_t)(n0 + r) * DMODEL + h * HDIM + d];
    }
    __syncthreads();
    for (int i = threadIdx.x; i < 64 * 64; i += 256) {
        int d = i >> 6, nn = i & 63;
        Kt[(size_t)(h * HDIM + d) * NTOK + n0 + nn] = T[nn][d];
    }
}

// ---------------------------------------------------------------------------
// score + top-2 per (n,h), transposed store idx_t[h*1024+n].
// g masked if n >= 64*g; ties -> lowest index; all-masked -> (0,1).
// ---------------------------------------------------------------------------
__global__ __launch_bounds__(256) void score_top2_kernel(
    const float* __restrict__ Q, const float* __restrict__ kc,
    int2* __restrict__ idx_t)
{
    const int t = blockIdx.x * 256 + threadIdx.x;   // t = n*16 + h
    const int n = t >> 4, h = t & 15;
    float q[HDIM];
    #pragma unroll
    for (int d = 0; d < HDIM; d++) q[d] = Q[(size_t)n * DMODEL + h * HDIM + d];
    float sc[NBLK];
    #pragma unroll
    for (int g = 0; g < NBLK; g++) {
        float s = 0.f;
        #pragma unroll
        for (int d = 0; d < HDIM; d++) s += q[d] * kc[g * DMODEL + h * HDIM + d];
        sc[g] = (n >= (g << 6)) ? -INFINITY : s;
    }
    int i1 = -1; float b1 = -INFINITY;
    #pragma unroll
    for (int g = 0; g < NBLK; g++) if (i1 < 0 || sc[g] > b1) { b1 = sc[g]; i1 = g; }
    int i2 = -1; float b2 = -INFINITY;
    #pragma unroll
    for (int g = 0; g < NBLK; g++) { if (g == i1) continue; if (i2 < 0 || sc[g] > b2) { b2 = sc[g]; i2 = g; } }
    idx_t[(h << 10) | n] = make_int2(i1, i2);
}

// ---------------------------------------------------------------------------
// FUSED attention: one wave per (n,h). inter (2 blocks) + causal intra +
// gated blend, in-place over Q. Kt coalesced; V coalesced.
// ---------------------------------------------------------------------------
__global__ __launch_bounds__(256) void attn_fused_kernel(
    float* __restrict__ Q, const float* __restrict__ Kt,
    const float* __restrict__ V, const int2* __restrict__ idx_t,
    const float2* __restrict__ gate)
{
    const int wave = threadIdx.x >> 6, lane = threadIdx.x & 63;
    const int gw = blockIdx.x * 4 + wave;   // = n*16 + h
    const int n = gw >> 4, h = gw & 15;
    const int qi = n & 63;
    const int rown = (n >> 6) * CHUNK;
    const int2 sel = idx_t[(h << 10) | n];
    const int r1 = sel.x * CHUNK, r2 = sel.y * CHUNK;

    const float qreg = Q[(size_t)n * DMODEL + h * HDIM + lane];
    const float* Kth = Kt + (size_t)h * HDIM * NTOK;

    float s0a = 0.f, s0b = 0.f, s1a = 0.f, s1b = 0.f, sia = 0.f, sib = 0.f;
    #pragma unroll 8
    for (int d = 0; d < HDIM; d += 2) {
        float qd0 = __shfl(qreg, d);
        float qd1 = __shfl(qreg, d + 1);
        const float* row0 = Kth + (size_t)d * NTOK;
        const float* row1 = row0 + NTOK;
        s0a += qd0 * row0[r1 + lane];
        s1a += qd0 * row0[r2 + lane];
        sia += qd0 * row0[rown + lane];
        s0b += qd1 * row1[r1 + lane];
        s1b += qd1 * row1[r2 + lane];
        sib += qd1 * row1[rown + lane];
    }
    const float s0 = (s0a + s0b) * 0.125f;
    const float s1 = (s1a + s1b) * 0.125f;
    const float si = (sia + sib) * 0.125f;

    float m = fmaxf(s0, s1);
    #pragma unroll
    for (int off = 32; off; off >>= 1) m = fmaxf(m, __shfl_xor(m, off));
    const float e0 = expf(s0 - m), e1 = expf(s1 - m);
    float sum = e0 + e1;
    #pragma unroll
    for (int off = 32; off; off >>= 1) sum += __shfl_xor(sum, off);

    float sim = (lane > qi) ? -INFINITY : si;
    float mi = sim;
    #pragma unroll
    for (int off = 32; off; off >>= 1) mi = fmaxf(mi, __shfl_xor(mi, off));
    const float ei = (lane > qi) ? 0.f : expf(si - mi);
    float sumi = ei;
    #pragma unroll
    for (int off = 32; off; off >>= 1) sumi += __shfl_xor(sumi, off);

    const float* Vh = V + h * HDIM + lane;
    float oa = 0.f, ob = 0.f, oi = 0.f;
    #pragma unroll 4
    for (int k = 0; k < CHUNK; k++) {
        oa += __shfl(e0, k) * Vh[(size_t)(r1 + k) * DMODEL];
        ob += __shfl(e1, k) * Vh[(size_t)(r2 + k) * DMODEL];
    }
    #pragma unroll 4
    for (int k = 0; k <= qi; k++) {
        oi += __shfl(ei, k) * Vh[(size_t)(rown + k) * DMODEL];
    }

    const float2 gt = gate[gw];
    const float val = gt.x * ((oa + ob) / sum) + gt.y * (oi / sumi);
    Q[(size_t)n * DMODEL + h * HDIM + lane] = val;
}

// ---------------------------------------------------------------------------
extern "C" void kernel_launch(void* const* d_in, const int* in_sizes, int n_in,
                              void* d_out, int out_size, void* d_ws, size_t ws_size,
                              hipStream_t stream)
{
    const float* x  = (const float*)d_in[0];
    const float* Wq = (const float*)d_in[1];
    const float* Wk = (const float*)d_in[2];
    const float* Wv = (const float*)d_in[3];
    const float* Wg = (const float*)d_in[4];
    const float* Wo = (const float*)d_in[5];

    const size_t M1 = (size_t)NTOK * DMODEL;   // 1M elems

    // workspace layout (~32.3 MB)
    float* Q       = (float*)d_ws;                    // 4 MB
    float* K       = Q + M1;                          // 4 MB
    float* V       = K + M1;                          // 4 MB
    float* Kt      = V + M1;                          // 4 MB
    float* kc      = Kt + M1;                         // 64 KB
    float2* gate   = (float2*)(kc + NBLK * DMODEL);   // 128 KB
    int2* idx_t    = (int2*)(gate + NTOK * NHEAD);    // 128 KB
    __hip_bfloat16* xh  = (__hip_bfloat16*)(idx_t + NTOK * NHEAD);  // 2 MB (later: o hi)
    __hip_bfloat16* xl  = xh + M1;                                   // 2 MB (later: o lo)
    __hip_bfloat16* W3h = xl + M1;                                   // 6 MB (later: Wo hi)
    __hip_bfloat16* W3l = W3h + 3 * M1;                              // 6 MB (later: Wo lo)

    const int CAST_BLOCKS = (int)(M1 / (256 * 4));

    // pre-split x and Wq/Wk/Wv
    cast_split_f32_bf16<<<CAST_BLOCKS, 256, 0, stream>>>(x,  xh,          xl,          (int)M1);
    cast_split_f32_bf16<<<CAST_BLOCKS, 256, 0, stream>>>(Wq, W3h,         W3l,         (int)M1);
    cast_split_f32_bf16<<<CAST_BLOCKS, 256, 0, stream>>>(Wk, W3h + M1,    W3l + M1,    (int)M1);
    cast_split_f32_bf16<<<CAST_BLOCKS, 256, 0, stream>>>(Wv, W3h + 2*M1,  W3l + 2*M1,  (int)M1);

    dim3 gqkv(48, 16);
    gemm_qkv_ps<<<gqkv, 256, 0, stream>>>(xh, xl, W3h, W3l, Q, K, V);

    gate_kernel<<<NTOK, 256, 0, stream>>>(x, Wg, gate);
    kcompress_kernel<<<NBLK, 256, 0, stream>>>(K, kc);
    transpose_k_kernel<<<256, 256, 0, stream>>>(K, Kt);
    score_top2_kernel<<<NTOK * NHEAD / 256, 256, 0, stream>>>(Q, kc, idx_t);
    attn_fused_kernel<<<NTOK * NHEAD / 4, 256, 0, stream>>>(Q, Kt, V, idx_t, gate);

    // split blended o (in Q) and Wo; reuse xh/xl and the front of W3h/W3l
    cast_split_f32_bf16<<<CAST_BLOCKS, 256, 0, stream>>>(Q,  xh,  xl,  (int)M1);
    cast_split_f32_bf16<<<CAST_BLOCKS, 256, 0, stream>>>(Wo, W3h, W3l, (int)M1);

    hipMemsetAsync(d_out, 0, M1 * sizeof(float), stream);
    dim3 gwo(16, 16, 2);
    gemm_wo_ps<<<gwo, 256, 0, stream>>>(xh, xl, W3h, W3l, (float*)d_out);
}